// Round 2
// baseline (354.917 us; speedup 1.0000x reference)
//
#include <hip/hip_runtime.h>
#include <stdint.h>

typedef uint16_t u16;
typedef __attribute__((ext_vector_type(8)))  __bf16    bf16x8;
typedef __attribute__((ext_vector_type(4)))  __bf16    bf16x4;
typedef __attribute__((ext_vector_type(8)))  uint16_t  u16x8;
typedef __attribute__((ext_vector_type(4)))  uint16_t  u16x4;
typedef __attribute__((ext_vector_type(4)))  float     f32x4;
typedef __attribute__((ext_vector_type(16))) float     f32x16;

#define LOG2E 1.44269504088896340736f
#define MFMA16(a, b, c) __builtin_amdgcn_mfma_f32_16x16x32_bf16((a), (b), (c), 0, 0, 0)
#define MFMA32(a, b, c) __builtin_amdgcn_mfma_f32_32x32x16_bf16((a), (b), (c), 0, 0, 0)

__device__ __forceinline__ u16 f2b(float f) {   // fp32 -> bf16 RNE
  uint32_t u = __builtin_bit_cast(uint32_t, f);
  u += 0x7fffu + ((u >> 16) & 1u);
  return (u16)(u >> 16);
}

// LDS tiles: [rows][64 bf16] = 8 chunks of 16B per row, chunk XOR-swizzled by row&7.
__device__ __forceinline__ bf16x8 ldsFrag(const u16* base, int row, int chunk) {
  const u16* p = base + row * 64 + ((chunk ^ (row & 7)) << 3);
  u16x8 raw = *(const u16x8*)p;
  return __builtin_bit_cast(bf16x8, raw);
}
__device__ __forceinline__ void ldsPut(u16* base, int row, int logicalChunk, u16x8 v) {
  u16* p = base + row * 64 + ((logicalChunk ^ (row & 7)) << 3);
  *(u16x8*)p = v;
}

// async global->LDS DMA, 16B per lane; LDS dest = wave-uniform base + lane*16.
__device__ __forceinline__ void dma16(const u16* g, u16* l) {
  __builtin_amdgcn_global_load_lds(
      (const __attribute__((address_space(1))) uint32_t*)g,
      (__attribute__((address_space(3))) uint32_t*)l, 16, 0, 0);
}

// ---------------- kernel 0: pack weights (coalesced read + LDS transpose) ----
// Wt[n][k] bf16 (n<64: Wf*log2e, n<128: Wg, else Wh), biasc[n] fp32 (bf*log2e).
__global__ __launch_bounds__(256) void pack_weights2(
    const float* __restrict__ Wf, const float* __restrict__ Wg,
    const float* __restrict__ Wh, const float* __restrict__ bfv,
    const float* __restrict__ bgv, const float* __restrict__ bhv,
    u16* __restrict__ Wt, float* __restrict__ biasc) {
  __shared__ u16 T[64 * 64];       // [k][n]
  const int nt = blockIdx.x >> 3;  // 0..9
  const int kt = blockIdx.x & 7;   // 0..7
  const int n0 = nt * 64, k0 = kt * 64;
  const float* src; int stride, cbase; float scale = 1.0f;
  if (nt == 0)      { src = Wf; stride = 64;  cbase = 0;        scale = LOG2E; }
  else if (nt == 1) { src = Wg; stride = 64;  cbase = 0; }
  else              { src = Wh; stride = 512; cbase = n0 - 128; }
  const int t = threadIdx.x;
  const int cl = (t & 15) * 4, r0 = t >> 4;
#pragma unroll
  for (int j = 0; j < 4; ++j) {
    int r = r0 + j * 16;
    f32x4 v = *(const f32x4*)(src + (size_t)(k0 + r) * stride + cbase + cl);
    u16x4 o;
#pragma unroll
    for (int i = 0; i < 4; ++i) o[i] = f2b(v[i] * scale);
    *(u16x4*)(T + r * 64 + cl) = o;
  }
  __syncthreads();
  const int n = t >> 2, kq = (t & 3) * 16;
  u16x8 a, b2;
#pragma unroll
  for (int i = 0; i < 8; ++i) { a[i] = T[(kq + i) * 64 + n]; b2[i] = T[(kq + 8 + i) * 64 + n]; }
  *(u16x8*)(Wt + (size_t)(n0 + n) * 512 + k0 + kq) = a;
  *(u16x8*)(Wt + (size_t)(n0 + n) * 512 + k0 + kq + 8) = b2;
  if (kt == 0 && t < 64) {
    float bv = (nt == 0) ? bfv[t] * LOG2E : (nt == 1) ? bgv[t] : bhv[cbase + t];
    biasc[n0 + t] = bv;
  }
}

// ---------------- kernel 1: projection GEMM ----------------
// [16384 x 512](x fp32->bf16) @ Wt^T -> f[m][64], g[m][64], ht[b][vcol][pos]
// h epilogue bounces through LDS so ht stores are coalesced 16B.
__global__ __launch_bounds__(256, 2) void proj_gemm(
    const float* __restrict__ x, const u16* __restrict__ Wt,
    const float* __restrict__ biasc,
    u16* __restrict__ fo, u16* __restrict__ go, u16* __restrict__ ht) {
  __shared__ u16 smem[128 * 128];          // 32KB: lds_a | lds_b, reused as T
  u16* lds_a = smem;
  u16* lds_b = smem + 128 * 64;
  const int t = threadIdx.x, lane = t & 63, wave = t >> 6;
  const int m0 = blockIdx.x * 128, n0 = blockIdx.y * 128;
  const int wr = wave >> 1, wc = wave & 1;
  const int l15 = lane & 15, l4 = lane >> 4;
  const int sr = t >> 3, sc = t & 7;

  f32x4 acc[4][4];
#pragma unroll
  for (int i = 0; i < 4; ++i)
#pragma unroll
    for (int j = 0; j < 4; ++j) acc[i][j] = (f32x4)(0.f);

  for (int kb = 0; kb < 8; ++kb) {
    const int k0 = kb * 64;
    if (kb) __syncthreads();
#pragma unroll
    for (int p = 0; p < 4; ++p) {          // stage A: x fp32 -> bf16
      int rr = p * 32 + sr;
      const float* s = x + (size_t)(m0 + rr) * 512 + k0 + sc * 8;
      f32x4 a0 = *(const f32x4*)s;
      f32x4 a1 = *(const f32x4*)(s + 4);
      u16x8 v;
#pragma unroll
      for (int i = 0; i < 4; ++i) { v[i] = f2b(a0[i]); v[4 + i] = f2b(a1[i]); }
      ldsPut(lds_a, rr, sc, v);
    }
#pragma unroll
    for (int p = 0; p < 4; ++p) {          // stage B: Wt bf16
      int rr = p * 32 + sr;
      u16x8 v = *(const u16x8*)(Wt + (size_t)(n0 + rr) * 512 + k0 + sc * 8);
      ldsPut(lds_b, rr, sc, v);
    }
    __syncthreads();
#pragma unroll
    for (int ks = 0; ks < 2; ++ks) {
      const int chunk = ks * 4 + l4;
      bf16x8 af[4], bq[4];
#pragma unroll
      for (int mt = 0; mt < 4; ++mt) af[mt] = ldsFrag(lds_a, wr * 64 + mt * 16 + l15, chunk);
#pragma unroll
      for (int nt = 0; nt < 4; ++nt) bq[nt] = ldsFrag(lds_b, wc * 64 + nt * 16 + l15, chunk);
#pragma unroll
      for (int mt = 0; mt < 4; ++mt)
#pragma unroll
        for (int nt = 0; nt < 4; ++nt) acc[mt][nt] = MFMA16(af[mt], bq[nt], acc[mt][nt]);
    }
  }

  if (n0 >= 128) {
    // ---- h path: LDS-bounce transpose, coalesced ht stores ----
    __syncthreads();                       // all MFMA LDS reads done
#pragma unroll
    for (int nt = 0; nt < 4; ++nt) {
      int nl = wc * 64 + nt * 16 + l15;    // n within block (0..127)
      float bv = biasc[n0 + nl];
#pragma unroll
      for (int mt = 0; mt < 4; ++mt) {
        int mb = wr * 64 + mt * 16 + (l4 << 2);
        f32x4 a = acc[mt][nt];
        u16x4 v;
#pragma unroll
        for (int r = 0; r < 4; ++r) v[r] = f2b(a[r] + bv);
        // T[nl][m], 16B-chunk swizzled by nl&7
        u16* dst = smem + nl * 128 + (((mb >> 3) ^ (nl & 7)) << 3) + (mb & 7);
        *(u16x4*)dst = v;
      }
    }
    __syncthreads();
    const int bb = m0 >> 12, posb = m0 & 4095;
    const int row0 = t >> 4, c16 = t & 15;
#pragma unroll
    for (int j = 0; j < 8; ++j) {
      int rr = row0 + j * 16;
      u16x8 v = *(const u16x8*)(smem + rr * 128 + ((c16 ^ (rr & 7)) << 3));
      int vcol = n0 - 128 + rr;
      *(u16x8*)(ht + ((size_t)(bb * 512 + vcol) << 12) + posb + c16 * 8) = v;
    }
  } else {
    // ---- f/g path ----
#pragma unroll
    for (int nt = 0; nt < 4; ++nt) {
      int n = wc * 64 + nt * 16 + l15;
      float bv = biasc[n];
#pragma unroll
      for (int mt = 0; mt < 4; ++mt) {
        int mrow = m0 + wr * 64 + mt * 16 + (l4 << 2);
        f32x4 a = acc[mt][nt];
        if (n < 64) {
#pragma unroll
          for (int r = 0; r < 4; ++r) fo[(size_t)(mrow + r) * 64 + n] = f2b(a[r] + bv);
        } else {
#pragma unroll
          for (int r = 0; r < 4; ++r) go[(size_t)(mrow + r) * 64 + (n - 64)] = f2b(a[r] + bv);
        }
      }
    }
  }
}

// ---------------- kernel 2: flash attention v5 (32x32, wave-local P bounce) --
// 1024 blocks (4/CU), 2 waves (128 thr). Block: 64 q x 128 c; wave: 32 q x 128 c.
// Kt=64 keys/iter, 64 iters. Swapped QK^T via mfma_32x32x16: D col = lane&31 = q.
// P is bounced through a PER-WAVE swizzled LDS tile (producer and consumer lanes
// are in the same wave -> no barrier, only lgkmcnt): D-reg -> bf16 u16x4 writes
// at verified D-row key positions, ds_read_b128 back as the PV A-frag. This
// replaces the permlane32_swap construction that failed verification in v4.
// g double-buffered in LDS via global_load_lds (pre-swizzled source); ONE
// __syncthreads per iter (its implicit vmcnt(0) retires the DMA). Row-sum is
// wave-private: shfl_xor(32) only. log2e folded into f at pack -> exp2 direct.
__global__ __launch_bounds__(128, 2) void attn5(
    const u16* __restrict__ fq, const u16* __restrict__ gk,
    const u16* __restrict__ ht, const float* __restrict__ x,
    const float* __restrict__ gamma_p, float* __restrict__ out) {
  __shared__ u16 lds_g[2][64 * 64];        // g dbuf, 16KB, swizzled
  __shared__ u16 lds_p[2][32 * 64];        // per-wave P tile, 8KB, swizzled
  __shared__ float lds_linv[2][32];

  const int i = blockIdx.x;                // 1024 blocks
  const int slice = i & 15;                // XCD x serves slices {x,x+8}: ~2MB ht in L2
  const int b = slice >> 2, vq = slice & 3;
  const int qb = i >> 4;                   // 0..63
  const int q0 = qb * 64, vc0 = vq * 128;

  const int t = threadIdx.x, lane = t & 63, w = t >> 6;
  const int l31 = lane & 31, hi = lane >> 5;
  const float gamma = gamma_p[0];
  const int dmarow = lane >> 3, dmachunk = (lane & 7) ^ (lane >> 3);

  const u16* gkb = gk + (size_t)(b * 4096) * 64;
  const u16* htw = ht + (size_t)(b * 512 + vc0) * 4096;
  u16* ldsp = lds_p[w];                    // wave-private

  // preload f B-frags: this wave's 32 q, d=64 as 4 k-steps of 16
  bf16x8 fB[4];
  {
    const u16* fb = fq + (size_t)(b * 4096 + q0 + w * 32 + l31) * 64 + hi * 8;
#pragma unroll
    for (int s = 0; s < 4; ++s)
      fB[s] = __builtin_bit_cast(bf16x8, *(const u16x8*)(fb + s * 16));
  }

  f32x16 oacc[4];                          // 4 c-tiles of 32; q rows per D layout
#pragma unroll
  for (int ct = 0; ct < 4; ++ct) oacc[ct] = (f32x16)(0.f);
  float lrun = 0.f;

  auto stage_g = [&](int k0g, u16* dst) {  // 64 keys x 64 d; wave stages 32 rows
#pragma unroll
    for (int ii = 0; ii < 4; ++ii) {
      int rw = w * 32 + ii * 8;
      dma16(gkb + (size_t)(k0g + rw + dmarow) * 64 + dmachunk * 8, dst + rw * 64);
    }
  };

  stage_g(0, lds_g[0]);
  __syncthreads();

  for (int kt = 0; kt < 64; ++kt) {
    const int k0 = kt * 64;
    const u16* gbuf = lds_g[kt & 1];
    if (kt < 63) stage_g(k0 + 64, lds_g[(kt & 1) ^ 1]);   // overlap DMA with whole iter

    // ---- S^T: D[key][q], two 32-key tiles; A=g from LDS, B=f pinned ----
    f32x16 sac[2];
#pragma unroll
    for (int kg = 0; kg < 2; ++kg) {
      f32x16 s = (f32x16)(0.f);
#pragma unroll
      for (int ss = 0; ss < 4; ++ss) {
        bf16x8 gA = ldsFrag(gbuf, kg * 32 + l31, ss * 2 + hi);
        s = MFMA32(gA, fB[ss], s);
      }
      sac[kg] = s;
    }

    // ---- per 32-key tile: hb loads -> exp2 -> P bounce (wave-local) -> PV ----
#pragma unroll
    for (int kg = 0; kg < 2; ++kg) {
      u16x8 hbr[2][4];                     // [16-key half][c-tile]
#pragma unroll
      for (int h = 0; h < 2; ++h)
#pragma unroll
        for (int ct = 0; ct < 4; ++ct)
          hbr[h][ct] = *(const u16x8*)(htw + (size_t)(ct * 32 + l31) * 4096 +
                                       k0 + kg * 32 + h * 16 + hi * 8);
      f32x16 p;
#pragma unroll
      for (int r = 0; r < 16; ++r) p[r] = __builtin_amdgcn_exp2f(sac[kg][r]);
      lrun += ((p[0] + p[1]) + (p[2] + p[3])) + ((p[4] + p[5]) + (p[6] + p[7])) +
              ((p[8] + p[9]) + (p[10] + p[11])) + ((p[12] + p[13]) + (p[14] + p[15]));
      // P write: D reg-quad Q (regs 4Q..4Q+3) = keys kg*32 + Q*8 + 4*hi + {0..3}
      // (m74/m101-verified row formula). Row = own q = l31; 16B-chunk swizzle.
#pragma unroll
      for (int Q = 0; Q < 4; ++Q) {
        bf16x4 pb;
#pragma unroll
        for (int r = 0; r < 4; ++r) pb[r] = (__bf16)p[4 * Q + r];
        int chunk = kg * 4 + Q;            // 8 keys per 16B chunk
        u16* dst = ldsp + l31 * 64 + ((chunk ^ (l31 & 7)) << 3) + 4 * hi;
        *(u16x4*)dst = __builtin_bit_cast(u16x4, pb);
      }
      // PV: A[q=l31][k_local=hi*8+j] <- one b128 per 16-key half (same wave
      // wrote it; compiler inserts the lgkmcnt wait). B = ht, position-paired.
#pragma unroll
      for (int h = 0; h < 2; ++h) {
        bf16x8 pa = ldsFrag(ldsp, l31, kg * 4 + h * 2 + hi);
#pragma unroll
        for (int ct = 0; ct < 4; ++ct)
          oacc[ct] = MFMA32(pa, __builtin_bit_cast(bf16x8, hbr[h][ct]), oacc[ct]);
      }
    }
    __syncthreads();                       // retires next-buf DMA; gbuf reads done
  }

  // ---- row-sum: wave-private (q = lane&31 on both halves) ----
  lrun += __shfl_xor(lrun, 32);
  if (lane < 32) lds_linv[w][l31] = 1.0f / lrun;
  __syncthreads();
  float linvv[16];
#pragma unroll
  for (int r = 0; r < 16; ++r)
    linvv[r] = lds_linv[w][(r & 3) + 8 * (r >> 2) + 4 * hi];   // broadcast reads

  // ---- epilogue: out = x + gamma * O / l ----
#pragma unroll
  for (int ct = 0; ct < 4; ++ct) {
    int c = vc0 + ct * 32 + l31;
#pragma unroll
    for (int r = 0; r < 16; ++r) {
      int q = q0 + w * 32 + (r & 3) + 8 * (r >> 2) + 4 * hi;
      size_t idx = ((size_t)(b * 4096 + q) << 9) + c;
      out[idx] = x[idx] + gamma * oacc[ct][r] * linvv[r];
    }
  }
}

extern "C" void kernel_launch(void* const* d_in, const int* in_sizes, int n_in,
                              void* d_out, int out_size, void* d_ws, size_t ws_size,
                              hipStream_t stream) {
  const float* x   = (const float*)d_in[0];
  const float* Wf  = (const float*)d_in[1];
  const float* bfv = (const float*)d_in[2];
  const float* Wg  = (const float*)d_in[3];
  const float* bgv = (const float*)d_in[4];
  const float* Wh  = (const float*)d_in[5];
  const float* bhv = (const float*)d_in[6];
  const float* gam = (const float*)d_in[7];
  float* out = (float*)d_out;

  char* ws = (char*)d_ws;                  // total scratch: ~21.6 MB
  u16*   Wt    = (u16*)(ws);               // 640*512*2   = 655360
  float* biasc = (float*)(ws + 655360);    // 640*4       = 2560
  u16*   fo    = (u16*)(ws + 657920);      // 16384*64*2  = 2097152
  u16*   go    = (u16*)(ws + 2755072);     // 2097152
  u16*   ht    = (u16*)(ws + 4852224);     // 4*512*4096*2 = 16777216

  pack_weights2<<<80, 256, 0, stream>>>(Wf, Wg, Wh, bfv, bgv, bhv, Wt, biasc);
  proj_gemm<<<dim3(128, 5), 256, 0, stream>>>(x, Wt, biasc, fo, go, ht);
  attn5<<<1024, 128, 0, stream>>>(fo, go, ht, x, gam, out);
}